// Round 8
// baseline (26522.015 us; speedup 1.0000x reference)
//
#include <hip/hip_runtime.h>
#include <math.h>

#define Bsz 1024
#define Lsz 50
#define Esz 256
#define Hsz 256
#define NEGV (-1e9f)

// ============================================================
// pack the two Wq matrices k-major once + zero the barrier counter.
// Wpk[((k>>2)*256 + n)*4 + (k&3)] = Wq[n][k]
// ============================================================
__global__ void pack_wq(const float* __restrict__ WqGl, const float* __restrict__ WqPt,
                        float* __restrict__ WqGlP, float* __restrict__ WqPtP,
                        unsigned* __restrict__ barrier_cnt)
{
    int k = blockIdx.x;
    int n = threadIdx.x;
    const float* src = blockIdx.y ? WqPt : WqGl;
    float*       dst = blockIdx.y ? WqPtP : WqGlP;
    dst[((size_t)(k >> 2) * 256 + n) * 4 + (k & 3)] = src[(size_t)n * 256 + k];
    if (blockIdx.x == 0 && blockIdx.y == 0 && threadIdx.x == 0) *barrier_cnt = 0u;
}

// ============================================================
// e-projection GEMM (one-time), both matrices (unchanged, passing).
// ============================================================
__global__ __launch_bounds__(256) void eproj_kernel(
    const float* __restrict__ A,
    const float* __restrict__ Wgl, const float* __restrict__ bgl, float* __restrict__ Egl,
    const float* __restrict__ Wpt, const float* __restrict__ bpt, float* __restrict__ Ept)
{
    __shared__ __align__(16) float As[16][68];
    __shared__ __align__(16) float Bs[16][68];
    const int tid = threadIdx.x;
    const int tx = tid & 15, ty = tid >> 4;
    const int ml = tid >> 2;
    const int kb = (tid & 3) << 2;

    const int x = blockIdx.x;
    const int xcd = x & 7;
    const int j = x >> 3;
    const int mt = xcd * 100 + (j >> 3);
    const int sel = (j >> 2) & 1;
    const int nt = j & 3;
    const float* W    = sel ? Wpt : Wgl;
    const float* bias = sel ? bpt : bgl;
    float*       Eo   = sel ? Ept : Egl;
    const int m0 = mt * 64, n0 = nt * 64;

    float4 a4 = *(const float4*)(A + (size_t)(m0 + ml) * 256 + kb);
    float4 b4 = *(const float4*)(W + (size_t)(n0 + ml) * 256 + kb);

    float acc[4][4] = {};
    for (int k0 = 0; k0 < 256; k0 += 16) {
        As[kb+0][ml] = a4.x; As[kb+1][ml] = a4.y; As[kb+2][ml] = a4.z; As[kb+3][ml] = a4.w;
        Bs[kb+0][ml] = b4.x; Bs[kb+1][ml] = b4.y; Bs[kb+2][ml] = b4.z; Bs[kb+3][ml] = b4.w;
        __syncthreads();
        int k1 = k0 + 16;
        if (k1 < 256) {
            a4 = *(const float4*)(A + (size_t)(m0 + ml) * 256 + k1 + kb);
            b4 = *(const float4*)(W + (size_t)(n0 + ml) * 256 + k1 + kb);
        }
#pragma unroll
        for (int kk = 0; kk < 16; kk++) {
            float4 av = *(const float4*)(&As[kk][ty << 2]);
            float4 bv = *(const float4*)(&Bs[kk][tx << 2]);
            float a_[4] = {av.x, av.y, av.z, av.w};
            float b_[4] = {bv.x, bv.y, bv.z, bv.w};
#pragma unroll
            for (int i = 0; i < 4; i++)
#pragma unroll
                for (int j2 = 0; j2 < 4; j2++) acc[i][j2] = fmaf(a_[i], b_[j2], acc[i][j2]);
        }
        __syncthreads();
    }
#pragma unroll
    for (int i = 0; i < 4; i++) {
        int m = m0 + (ty << 2) + i;
        int bb = m & (Bsz - 1);
        int ll = m >> 10;
#pragma unroll
        for (int j2 = 0; j2 < 4; j2++) {
            int n = n0 + (tx << 2) + j2;
            Eo[(size_t)bb * Lsz * Hsz + (size_t)ll * Hsz + n] = acc[i][j2] + bias[n];
        }
    }
}

// ============================================================
// DIY device-wide barrier.  Safe because the decode kernel's grid is sized
// to be fully co-resident by construction (VGPR<=128 via launch_bounds
// (256,4) -> exactly 4 blocks/CU; LDS 8.4KB << 40KB/block budget).
// Monotone target, no counter reset; counter zeroed by pack_wq each call.
// ============================================================
__device__ __forceinline__ void grid_barrier(unsigned* cnt, unsigned& tgt)
{
    __threadfence();            // each thread's prior writes -> device scope
    __syncthreads();            // all block threads arrived
    tgt += gridDim.x;
    if (threadIdx.x == 0) {
        __hip_atomic_fetch_add(cnt, 1u, __ATOMIC_RELEASE, __HIP_MEMORY_SCOPE_AGENT);
        while (__hip_atomic_load(cnt, __ATOMIC_ACQUIRE, __HIP_MEMORY_SCOPE_AGENT) < tgt) {
            __builtin_amdgcn_s_sleep(1);
        }
    }
    __syncthreads();
}

// ============================================================
// Persistent decode kernel: entire 50-step loop, plain launch.
// grid = min(1024, 4*CUs) blocks x 256 threads, grid-stride phase loops.
// Phase A: LSTM tiles (32 rows x 8 hidden units, ascending-k chain,
// bit-identical to round 6).  Phase B: fused attention per batch row
// (bit-identical to round 6 attn_row).  2 barriers per step.
// ============================================================
__global__ __launch_bounds__(256, 4) void decode_kernel(
    const float* __restrict__ dec0, const float* __restrict__ emb,
    const float* __restrict__ h0, const float* __restrict__ c0,
    const float* __restrict__ Wih, const float* __restrict__ Whh,
    const float* __restrict__ bih, const float* __restrict__ bhh,
    const float* __restrict__ WqGlP, const float* __restrict__ glbq,
    const float* __restrict__ e_gl, const float* __restrict__ glv,
    const float* __restrict__ WqPtP, const float* __restrict__ ptbq,
    const float* __restrict__ e_pt, const float* __restrict__ ptv,
    float* hb0, float* hb1, float* cb0, float* cb1,
    float* dec, int* mask, float* out, unsigned* barrier_cnt)
{
    __shared__ __align__(16) float As[16][36];
    __shared__ __align__(16) float Bs[16][36];
    __shared__ __align__(16) float h_s[256];
    __shared__ __align__(16) float q_s[256];
    __shared__ __align__(16) float g_s[256];
    __shared__ float u_s[64];
    __shared__ float p_s[64];
    __shared__ int sel_s;

    const int tid = threadIdx.x;
    const int lane = tid & 63, wave = tid >> 6;
    unsigned bar_tgt = 0;

    // ---- init: decoder input copy + mask clear (grid-stride) ----
    for (int b = blockIdx.x; b < Bsz; b += gridDim.x) {
        dec[(size_t)b * 256 + tid] = dec0[(size_t)b * 256 + tid];
        if (tid < Lsz) mask[b * Lsz + tid] = 0;
    }

    // LSTM thread constants (independent of tile index)
    const int mlA = tid >> 3, kbA = (tid & 7) << 1;
    const int mlB = tid >> 3, kbB = (tid & 7) << 1;
    const int tx = tid & 7, ty = tid >> 3;

    grid_barrier(barrier_cnt, bar_tgt);

    for (int t = 0; t < Lsz; t++) {
        const float* hin = (t == 0) ? h0 : ((t & 1) ? hb0 : hb1);
        const float* cin = (t == 0) ? c0 : ((t & 1) ? cb0 : cb1);
        float* hout = (t & 1) ? hb1 : hb0;
        float* cout = (t & 1) ? cb1 : cb0;

        // ================= phase A: LSTM (tiled GEMM + gate epilogue) ====
        for (int tl = blockIdx.x; tl < 1024; tl += gridDim.x) {
            const int m0 = (tl >> 5) * 32;
            const int hh0 = (tl & 31) * 8;
            const int wrow = (mlB & 3) * 256 + hh0 + (mlB >> 2);
            const int hh = hh0 + tx;

            float2 a2 = *(const float2*)(dec + (size_t)(m0 + mlA) * 256 + kbA);
            float2 b2 = *(const float2*)(Wih + (size_t)wrow * 256 + kbB);
            float ac0 = 0.0f, ac1 = 0.0f, ac2 = 0.0f, ac3 = 0.0f;
            for (int k0 = 0; k0 < 512; k0 += 16) {
                As[kbA+0][mlA] = a2.x; As[kbA+1][mlA] = a2.y;
                Bs[kbB+0][mlB] = b2.x; Bs[kbB+1][mlB] = b2.y;
                __syncthreads();
                int k1 = k0 + 16;
                if (k1 < 512) {
                    const float* Ap = (k1 < 256) ? dec : hin;
                    const float* Wp = (k1 < 256) ? Wih : Whh;
                    int kk0 = k1 & 255;
                    a2 = *(const float2*)(Ap + (size_t)(m0 + mlA) * 256 + kk0 + kbA);
                    b2 = *(const float2*)(Wp + (size_t)wrow * 256 + kk0 + kbB);
                }
#pragma unroll
                for (int kk = 0; kk < 16; kk++) {
                    float av = As[kk][ty];
                    float4 bv = *(const float4*)(&Bs[kk][tx << 2]);
                    ac0 = fmaf(av, bv.x, ac0);
                    ac1 = fmaf(av, bv.y, ac1);
                    ac2 = fmaf(av, bv.z, ac2);
                    ac3 = fmaf(av, bv.w, ac3);
                }
                __syncthreads();
            }
            const float bi0 = bih[hh]       + bhh[hh];
            const float bf  = bih[256 + hh] + bhh[256 + hh];
            const float bg  = bih[512 + hh] + bhh[512 + hh];
            const float bo  = bih[768 + hh] + bhh[768 + hh];
            const int m = m0 + ty;
            float gi = ac0 + bi0;
            float gf = ac1 + bf;
            float gc = ac2 + bg;
            float go = ac3 + bo;
            float ii = 1.0f / (1.0f + expf(-gi));
            float ff = 1.0f / (1.0f + expf(-gf));
            float oo = 1.0f / (1.0f + expf(-go));
            float c2 = ff * cin[(size_t)m * 256 + hh] + ii * tanhf(gc);
            hout[(size_t)m * 256 + hh] = oo * tanhf(c2);
            cout[(size_t)m * 256 + hh] = c2;
        }

        grid_barrier(barrier_cnt, bar_tgt);

        // ================= phase B: fused attention per batch row ========
        for (int b = blockIdx.x; b < Bsz; b += gridDim.x) {
            h_s[tid] = hout[(size_t)b * 256 + tid];
            __syncthreads();

            // glimpse query matvec (packed weights)
            {
                float q = glbq[tid];
                const float4* Wp = (const float4*)WqGlP;
#pragma unroll 8
                for (int k4 = 0; k4 < 64; k4++) {
                    float4 w  = Wp[(size_t)k4 * 256 + tid];
                    float4 hv = ((const float4*)h_s)[k4];
                    q = fmaf(hv.x, w.x, q);
                    q = fmaf(hv.y, w.y, q);
                    q = fmaf(hv.z, w.z, q);
                    q = fmaf(hv.w, w.w, q);
                }
                q_s[tid] = q;
            }
            __syncthreads();

            const float* ebg = e_gl + (size_t)b * Lsz * 256;
            {
                const float4 q4 = ((const float4*)q_s)[lane];
                const float4 v4 = ((const float4*)glv)[lane];
#pragma unroll
                for (int lp = 0; lp < 13; lp++) {
                    const int l = lp * 4 + wave;
                    float x = 0.0f;
                    if (l < Lsz) {
                        float4 e4 = *(const float4*)(ebg + (size_t)l * 256 + (lane << 2));
                        x  = v4.x * tanhf(q4.x + e4.x);
                        x += v4.y * tanhf(q4.y + e4.y);
                        x += v4.z * tanhf(q4.z + e4.z);
                        x += v4.w * tanhf(q4.w + e4.w);
                    }
#pragma unroll
                    for (int o = 32; o > 0; o >>= 1) x += __shfl_xor(x, o, 64);
                    if (lane == 0 && l < Lsz) u_s[l] = x;
                }
            }
            __syncthreads();

            // glimpse softmax (wave 0)
            if (wave == 0) {
                const int l = lane;
                const int ml = (l < Lsz) ? mask[b * Lsz + l] : 0;
                float logit = (l < Lsz) ? (ml ? NEGV : u_s[l]) : -1e30f;
                float m = logit;
#pragma unroll
                for (int o = 32; o > 0; o >>= 1) m = fmaxf(m, __shfl_xor(m, o, 64));
                float ex = (l < Lsz) ? expf(logit - m) : 0.0f;
                float den = ex;
#pragma unroll
                for (int o = 32; o > 0; o >>= 1) den += __shfl_xor(den, o, 64);
                if (l < Lsz) p_s[l] = ex / den;
            }
            __syncthreads();

            // glimpse mix
            {
                float acc = 0.0f;
                const float* ebh = ebg + tid;
#pragma unroll
                for (int l = 0; l < Lsz; l++)
                    acc = fmaf(p_s[l], ebh[(size_t)l * 256], acc);
                g_s[tid] = acc;
            }
            __syncthreads();

            // pointer query matvec (packed weights)
            {
                float p = ptbq[tid];
                const float4* Wp = (const float4*)WqPtP;
#pragma unroll 8
                for (int k4 = 0; k4 < 64; k4++) {
                    float4 w  = Wp[(size_t)k4 * 256 + tid];
                    float4 gv = ((const float4*)g_s)[k4];
                    p = fmaf(gv.x, w.x, p);
                    p = fmaf(gv.y, w.y, p);
                    p = fmaf(gv.z, w.z, p);
                    p = fmaf(gv.w, w.w, p);
                }
                q_s[tid] = p;
            }
            __syncthreads();

            const float* ebp = e_pt + (size_t)b * Lsz * 256;
            {
                const float4 q4 = ((const float4*)q_s)[lane];
                const float4 v4 = ((const float4*)ptv)[lane];
#pragma unroll
                for (int lp = 0; lp < 13; lp++) {
                    const int l = lp * 4 + wave;
                    float x = 0.0f;
                    if (l < Lsz) {
                        float4 e4 = *(const float4*)(ebp + (size_t)l * 256 + (lane << 2));
                        x  = v4.x * tanhf(q4.x + e4.x);
                        x += v4.y * tanhf(q4.y + e4.y);
                        x += v4.z * tanhf(q4.z + e4.z);
                        x += v4.w * tanhf(q4.w + e4.w);
                    }
#pragma unroll
                    for (int o = 32; o > 0; o >>= 1) x += __shfl_xor(x, o, 64);
                    if (lane == 0 && l < Lsz) u_s[l] = x;
                }
            }
            __syncthreads();

            // pointer softmax + argmax + log_p + mask update (wave 0)
            if (wave == 0) {
                const int l = lane;
                const int ml = (l < Lsz) ? mask[b * Lsz + l] : 0;
                float logit;
                if (l < Lsz) {
                    float u = u_s[l];
                    logit = 10.0f * tanhf(u);
                    if (ml) logit = NEGV;
                } else logit = -1e30f;

                float m = logit;
#pragma unroll
                for (int o = 32; o > 0; o >>= 1) m = fmaxf(m, __shfl_xor(m, o, 64));
                float ex = (l < Lsz) ? expf(logit - m) : 0.0f;
                float den = ex;
#pragma unroll
                for (int o = 32; o > 0; o >>= 1) den += __shfl_xor(den, o, 64);

                float av = logit; int ai = (l < Lsz) ? l : 63;
#pragma unroll
                for (int o = 32; o > 0; o >>= 1) {
                    float ov = __shfl_xor(av, o, 64);
                    int   oi = __shfl_xor(ai, o, 64);
                    if (ov > av || (ov == av && oi < ai)) { av = ov; ai = oi; }
                }
                const float lse = m + logf(den);
                if (l < Lsz)
                    out[(size_t)b * Lsz * Lsz + (size_t)t * Lsz + l] = logit - lse;
                if (l == 0) {
                    out[(size_t)Bsz * Lsz * Lsz + (size_t)b * Lsz + t] = (float)ai;
                    sel_s = ai;
                }
                int newm = ml | (l == ai);
                unsigned long long bal = __ballot(l >= Lsz ? 1 : newm);
                int all = (bal == 0xFFFFFFFFFFFFFFFFull);
                if (l < Lsz) mask[b * Lsz + l] = (all && l == Lsz - 1) ? 0 : newm;
            }
            __syncthreads();

            // gather next decoder input
            {
                const int s = sel_s;
                dec[(size_t)b * 256 + tid] = emb[(size_t)s * Bsz * 256 + (size_t)b * 256 + tid];
            }
            __syncthreads();
        }

        grid_barrier(barrier_cnt, bar_tgt);
    }
}

// ============================================================
extern "C" void kernel_launch(void* const* d_in, const int* in_sizes, int n_in,
                              void* d_out, int out_size, void* d_ws, size_t ws_size,
                              hipStream_t stream) {
    const float* decoder_input = (const float*)d_in[0];
    const float* emb           = (const float*)d_in[1];   // [L,B,E]
    const float* h0            = (const float*)d_in[2];
    const float* c0            = (const float*)d_in[3];
    const float* context       = (const float*)d_in[4];   // [L,B,H]
    const float* Wih    = (const float*)d_in[6];
    const float* Whh    = (const float*)d_in[7];
    const float* bih    = (const float*)d_in[8];
    const float* bhh    = (const float*)d_in[9];
    const float* glWq   = (const float*)d_in[10];
    const float* glbq   = (const float*)d_in[11];
    const float* glWref = (const float*)d_in[12];
    const float* glbref = (const float*)d_in[13];
    const float* glv    = (const float*)d_in[14];
    const float* ptWq   = (const float*)d_in[15];
    const float* ptbq   = (const float*)d_in[16];
    const float* ptWref = (const float*)d_in[17];
    const float* ptbref = (const float*)d_in[18];
    const float* ptv    = (const float*)d_in[19];

    float* out = (float*)d_out;

    // workspace layout (floats)
    float* ws    = (float*)d_ws;
    float* e_gl  = ws;                                    // [B,L,H]
    float* e_pt  = e_gl + (size_t)Bsz * Lsz * Hsz;        // [B,L,H]
    float* WqGlP = e_pt + (size_t)Bsz * Lsz * Hsz;        // [H,H] packed
    float* WqPtP = WqGlP + (size_t)Hsz * Hsz;
    float* hb0   = WqPtP + (size_t)Hsz * Hsz;
    float* hb1   = hb0 + (size_t)Bsz * Hsz;
    float* cb0   = hb1 + (size_t)Bsz * Hsz;
    float* cb1   = cb0 + (size_t)Bsz * Hsz;
    float* dec   = cb1 + (size_t)Bsz * Hsz;
    int*   mask  = (int*)(dec + (size_t)Bsz * Esz);       // [B,L]
    unsigned* barrier_cnt = (unsigned*)(mask + Bsz * Lsz);

    // grid sized for guaranteed co-residency: 4 blocks/CU (VGPR<=128 forced)
    int cu = 256;
    hipDeviceGetAttribute(&cu, hipDeviceAttributeMultiprocessorCount, 0);
    int nblk = cu * 4;
    if (nblk > 1024) nblk = 1024;

    pack_wq<<<dim3(256, 2), dim3(256), 0, stream>>>(glWq, ptWq, WqGlP, WqPtP, barrier_cnt);

    eproj_kernel<<<dim3(6400), dim3(256), 0, stream>>>(
        context, glWref, glbref, e_gl, ptWref, ptbref, e_pt);

    decode_kernel<<<dim3(nblk), dim3(256), 0, stream>>>(
        decoder_input, emb, h0, c0, Wih, Whh, bih, bhh,
        WqGlP, glbq, e_gl, glv, WqPtP, ptbq, e_pt, ptv,
        hb0, hb1, cb0, cb1, dec, mask, out, barrier_cnt);
}